// Round 4
// baseline (201.759 us; speedup 1.0000x reference)
//
#include <hip/hip_runtime.h>

#define NB 4
#define NS 1024
#define NH 16
#define ND 64

typedef __attribute__((ext_vector_type(8))) short bf16x8;
typedef __attribute__((ext_vector_type(4))) float f32x4;

__device__ __forceinline__ short f2bf(float x) {
  __bf16 h = (__bf16)x;
  return __builtin_bit_cast(short, h);
}
__device__ __forceinline__ float bf2f(short s) {
  unsigned u = ((unsigned)(unsigned short)s) << 16;
  return __builtin_bit_cast(float, u);
}

__global__ __launch_bounds__(256, 4)
void fsa_fwd(const float* __restrict__ qkv,
             const float* __restrict__ bias,
             float* __restrict__ out)
{
  // XCD-chunked swizzle, batch-fastest logical order (round-3, kept).
  const int hw = blockIdx.x;
  const int lg = ((hw & 7) << 7) | (hw >> 3);
  const int b  = lg & 3;
  const int qt = (lg >> 2) & 15;
  const int h  = lg >> 6;

  const int tid  = threadIdx.x;
  const int w    = tid >> 6;
  const int lane = tid & 63;
  const int lo   = lane & 15;
  const int hi   = lane >> 4;
  const int q0   = qt * 64;

  __shared__ __attribute__((aligned(16))) short Ksh[2][64 * 64];   // XOR-swizzled rows
  __shared__ __attribute__((aligned(16))) short VTsh[2][64 * 64];  // [d][t] XOR-swizzled
  __shared__ __attribute__((aligned(16))) short Psh[4][16 * 64];   // per-wave P strip

  // ---- Q fragments, pre-scaled by 1/8 ----
  bf16x8 qf[2];
  {
    const int qs = q0 + w * 16 + lo;
    const float* qp = qkv + ((size_t)(b * NS + qs) * 3) * (NH * ND) + h * ND + hi * 8;
    #pragma unroll
    for (int f = 0; f < 2; ++f) {
      float4 x0 = *(const float4*)(qp + f * 32);
      float4 x1 = *(const float4*)(qp + f * 32 + 4);
      float v[8] = {x0.x, x0.y, x0.z, x0.w, x1.x, x1.y, x1.z, x1.w};
      #pragma unroll
      for (int j = 0; j < 8; ++j) qf[f][j] = f2bf(v[j] * 0.125f);
    }
  }

  const size_t tstr = 3 * NH * ND;
  const float* kgp = qkv + (size_t)b * NS * tstr + 1 * NH * ND + h * ND;
  const float* vgp = qkv + (size_t)b * NS * tstr + 2 * NH * ND + h * ND;

  const int krow = tid >> 2;          // 0..63
  const int kd   = (tid & 3) * 16;    // 16 floats
  const int vrow = (tid & 31) * 2;    // t pair
  const int vd   = (tid >> 5) * 8;    // 8 d's

  const float* bb = bias + (size_t)h * NS * NS + (size_t)(q0 + w * 16 + hi * 4) * NS + lo;

  float psum[4] = {0.f, 0.f, 0.f, 0.f};
  f32x4 oacc[4];
  #pragma unroll
  for (int dt = 0; dt < 4; ++dt) { f32x4 z = {0.f, 0.f, 0.f, 0.f}; oacc[dt] = z; }

  // prefetch regs
  float4 ka, kc, ke, kg4, va0, va1, vb0, vb1;
  float brA[4][4], brB[4][4];

#define LOAD_KV(T0) do { \
    const float* src_ = kgp + (size_t)((T0) + krow) * tstr + kd; \
    ka  = ((const float4*)src_)[0]; kc  = ((const float4*)src_)[1]; \
    ke  = ((const float4*)src_)[2]; kg4 = ((const float4*)src_)[3]; \
    const float* s0_ = vgp + (size_t)((T0) + vrow) * tstr + vd; \
    const float* s1_ = s0_ + tstr; \
    va0 = ((const float4*)s0_)[0]; va1 = ((const float4*)s0_)[1]; \
    vb0 = ((const float4*)s1_)[0]; vb1 = ((const float4*)s1_)[1]; \
  } while (0)

#define LOAD_BIAS(T0, BR) do { \
    _Pragma("unroll") \
    for (int r_ = 0; r_ < 4; ++r_) { \
      _Pragma("unroll") \
      for (int tt_ = 0; tt_ < 4; ++tt_) \
        BR[r_][tt_] = bb[(size_t)r_ * NS + (T0) + tt_ * 16]; \
    } \
  } while (0)

#define STAGE(NXT) do { \
    bf16x8 w0_, w1_; \
    { \
      float v_[16] = {ka.x,ka.y,ka.z,ka.w, kc.x,kc.y,kc.z,kc.w, \
                      ke.x,ke.y,ke.z,ke.w, kg4.x,kg4.y,kg4.z,kg4.w}; \
      _Pragma("unroll") \
      for (int j_ = 0; j_ < 8; ++j_) { w0_[j_] = f2bf(v_[j_]); w1_[j_] = f2bf(v_[8+j_]); } \
    } \
    { \
      const int base_ = krow * 64 + kd; \
      const int sw_ = (krow & 7) << 3; \
      *(bf16x8*)&Ksh[NXT][(base_    ) ^ sw_] = w0_; \
      *(bf16x8*)&Ksh[NXT][(base_ + 8) ^ sw_] = w1_; \
    } \
    { \
      float r0_[8] = {va0.x,va0.y,va0.z,va0.w, va1.x,va1.y,va1.z,va1.w}; \
      float r1_[8] = {vb0.x,vb0.y,vb0.z,vb0.w, vb1.x,vb1.y,vb1.z,vb1.w}; \
      unsigned* vt_ = (unsigned*)VTsh[NXT]; \
      _Pragma("unroll") \
      for (int j_ = 0; j_ < 8; ++j_) { \
        unsigned pk_ = (unsigned)(unsigned short)f2bf(r0_[j_]) | \
                       ((unsigned)(unsigned short)f2bf(r1_[j_]) << 16); \
        const int R_ = vd + j_; \
        vt_[R_ * 32 + ((vrow >> 1) ^ ((R_ & 7) << 2))] = pk_; \
      } \
    } \
  } while (0)

#define ITER(CUR, NXT, BR, T) do { \
    if ((T) < 15) STAGE(NXT); \
    f32x4 sacc[4]; \
    _Pragma("unroll") \
    for (int tt = 0; tt < 4; ++tt) { \
      _Pragma("unroll") \
      for (int r = 0; r < 4; ++r) sacc[tt][r] = BR[r][tt] - 8.f; \
    } \
    if ((T) < 14) { LOAD_KV(((T)+2) * 64); LOAD_BIAS(((T)+2) * 64, BR); } \
    _Pragma("unroll") \
    for (int tt = 0; tt < 4; ++tt) { \
      const int kr = tt * 16 + lo; \
      const int ksw = (kr & 7) << 3; \
      bf16x8 k0 = *(const bf16x8*)&Ksh[CUR][(kr * 64      + hi * 8) ^ ksw]; \
      bf16x8 k1 = *(const bf16x8*)&Ksh[CUR][(kr * 64 + 32 + hi * 8) ^ ksw]; \
      sacc[tt] = __builtin_amdgcn_mfma_f32_16x16x32_bf16(qf[0], k0, sacc[tt], 0, 0, 0); \
      sacc[tt] = __builtin_amdgcn_mfma_f32_16x16x32_bf16(qf[1], k1, sacc[tt], 0, 0, 0); \
    } \
    { \
      short* pw = Psh[w]; \
      _Pragma("unroll") \
      for (int r = 0; r < 4; ++r) { \
        const int row = hi * 4 + r; \
        const int sw = (row & 7) << 3; \
        _Pragma("unroll") \
        for (int tt = 0; tt < 4; ++tt) { \
          float p = __expf(sacc[tt][r]); \
          short pb = f2bf(p); \
          psum[r] += bf2f(pb); \
          pw[row * 64 + ((tt * 16 + lo) ^ sw)] = pb; \
        } \
      } \
      asm volatile("s_waitcnt lgkmcnt(0)" ::: "memory"); \
      bf16x8 pf0, pf1; \
      { \
        const int psw = (lo & 7) << 3; \
        pf0 = *(const bf16x8*)&pw[lo * 64 + ((     hi * 8) ^ psw)]; \
        pf1 = *(const bf16x8*)&pw[lo * 64 + ((32 + hi * 8) ^ psw)]; \
      } \
      _Pragma("unroll") \
      for (int dt = 0; dt < 4; ++dt) { \
        const int vr = dt * 16 + lo; \
        const int vsw = (vr & 7) << 3; \
        bf16x8 v0 = *(const bf16x8*)&VTsh[CUR][vr * 64 + ((     hi * 8) ^ vsw)]; \
        bf16x8 v1 = *(const bf16x8*)&VTsh[CUR][vr * 64 + ((32 + hi * 8) ^ vsw)]; \
        oacc[dt] = __builtin_amdgcn_mfma_f32_16x16x32_bf16(pf0, v0, oacc[dt], 0, 0, 0); \
        oacc[dt] = __builtin_amdgcn_mfma_f32_16x16x32_bf16(pf1, v1, oacc[dt], 0, 0, 0); \
      } \
    } \
    __syncthreads(); \
  } while (0)

  // ---- prologue: stage tile 0, prefetch tile 1 ----
  LOAD_KV(0);
  LOAD_BIAS(0, brA);
  STAGE(0);
  LOAD_KV(64);
  LOAD_BIAS(64, brB);
  __syncthreads();

  for (int t = 0; t < 16; t += 2) {
    ITER(0, 1, brA, t);
    ITER(1, 0, brB, t + 1);
  }

#undef ITER
#undef STAGE
#undef LOAD_BIAS
#undef LOAD_KV

  // ---- final row-sum reduction ----
  #pragma unroll
  for (int r = 0; r < 4; ++r) {
    psum[r] += __shfl_xor(psum[r], 1, 64);
    psum[r] += __shfl_xor(psum[r], 2, 64);
    psum[r] += __shfl_xor(psum[r], 4, 64);
    psum[r] += __shfl_xor(psum[r], 8, 64);
  }

  // ---- epilogue ----
  float* ob = out + ((size_t)(b * NS + q0 + w * 16 + hi * 4) * NH + h) * ND + lo;
  #pragma unroll
  for (int r = 0; r < 4; ++r) {
    float inv = 1.f / psum[r];
    #pragma unroll
    for (int dt = 0; dt < 4; ++dt)
      ob[(size_t)r * NH * ND + dt * 16] = oacc[dt][r] * inv;
  }
}

extern "C" void kernel_launch(void* const* d_in, const int* in_sizes, int n_in,
                              void* d_out, int out_size, void* d_ws, size_t ws_size,
                              hipStream_t stream) {
  const float* qkv  = (const float*)d_in[0];
  const float* bias = (const float*)d_in[1];
  float* out = (float*)d_out;
  dim3 grid(NB * NH * (NS / 64));
  fsa_fwd<<<grid, 256, 0, stream>>>(qkv, bias, out);
}

// Round 5
// 75.196 us; speedup vs baseline: 2.6831x; 2.6831x over previous
//
#include <hip/hip_runtime.h>

#define NB 4
#define NS 1024
#define NH 16
#define ND 64

typedef __attribute__((ext_vector_type(8))) short bf16x8;
typedef __attribute__((ext_vector_type(4))) float f32x4;

__device__ __forceinline__ short f2bf(float x) {
  __bf16 h = (__bf16)x;
  return __builtin_bit_cast(short, h);
}
__device__ __forceinline__ float bf2f(short s) {
  unsigned u = ((unsigned)(unsigned short)s) << 16;
  return __builtin_bit_cast(float, u);
}

__global__ __launch_bounds__(256, 2)
void fsa_fwd(const float* __restrict__ qkv,
             const float* __restrict__ bias,
             float* __restrict__ out)
{
  // XCD-chunked swizzle, batch-fastest logical order (round-3, kept).
  const int hw = blockIdx.x;
  const int lg = ((hw & 7) << 7) | (hw >> 3);
  const int b  = lg & 3;
  const int qt = (lg >> 2) & 15;
  const int h  = lg >> 6;

  const int tid  = threadIdx.x;
  const int w    = tid >> 6;
  const int lane = tid & 63;
  const int lo   = lane & 15;
  const int hi   = lane >> 4;
  const int q0   = qt * 64;

  __shared__ __attribute__((aligned(16))) short Ksh[2][64 * 64];   // XOR-swizzled rows
  __shared__ __attribute__((aligned(16))) short VTsh[2][64 * 64];  // [d][t] XOR-swizzled (conflict-free)
  __shared__ __attribute__((aligned(16))) short Psh[4][16 * 64];   // per-wave P strip

  // ---- Q fragments, pre-scaled by 1/8 ----
  bf16x8 qf[2];
  {
    const int qs = q0 + w * 16 + lo;
    const float* qp = qkv + ((size_t)(b * NS + qs) * 3) * (NH * ND) + h * ND + hi * 8;
    #pragma unroll
    for (int f = 0; f < 2; ++f) {
      float4 x0 = *(const float4*)(qp + f * 32);
      float4 x1 = *(const float4*)(qp + f * 32 + 4);
      float v[8] = {x0.x, x0.y, x0.z, x0.w, x1.x, x1.y, x1.z, x1.w};
      #pragma unroll
      for (int j = 0; j < 8; ++j) qf[f][j] = f2bf(v[j] * 0.125f);
    }
  }

  const size_t tstr = 3 * NH * ND;
  const float* kgp = qkv + (size_t)b * NS * tstr + 1 * NH * ND + h * ND;
  const float* vgp = qkv + (size_t)b * NS * tstr + 2 * NH * ND + h * ND;

  const int krow = tid >> 2;          // 0..63
  const int kd   = (tid & 3) * 16;    // 16 floats
  const int vrow = (tid & 31) * 2;    // t pair
  const int vd   = (tid >> 5) * 8;    // 8 d's

  const float* bb = bias + (size_t)h * NS * NS + (size_t)(q0 + w * 16 + hi * 4) * NS + lo;

  float psum[4] = {0.f, 0.f, 0.f, 0.f};
  f32x4 oacc[4];
  #pragma unroll
  for (int dt = 0; dt < 4; ++dt) { f32x4 z = {0.f, 0.f, 0.f, 0.f}; oacc[dt] = z; }

  // single prefetch register set: K/V hold tile t+1 entering iter t;
  // br holds tile t's bias entering iter t.
  float4 ka, kc, ke, kg4, va0, va1, vb0, vb1;
  float br[4][4];

#define LOAD_KV(T0) do { \
    const float* src_ = kgp + (size_t)((T0) + krow) * tstr + kd; \
    ka  = ((const float4*)src_)[0]; kc  = ((const float4*)src_)[1]; \
    ke  = ((const float4*)src_)[2]; kg4 = ((const float4*)src_)[3]; \
    const float* s0_ = vgp + (size_t)((T0) + vrow) * tstr + vd; \
    const float* s1_ = s0_ + tstr; \
    va0 = ((const float4*)s0_)[0]; va1 = ((const float4*)s0_)[1]; \
    vb0 = ((const float4*)s1_)[0]; vb1 = ((const float4*)s1_)[1]; \
  } while (0)

#define LOAD_BIAS(T0) do { \
    _Pragma("unroll") \
    for (int r_ = 0; r_ < 4; ++r_) { \
      _Pragma("unroll") \
      for (int tt_ = 0; tt_ < 4; ++tt_) \
        br[r_][tt_] = bb[(size_t)r_ * NS + (T0) + tt_ * 16]; \
    } \
  } while (0)

#define STAGE(NXT) do { \
    bf16x8 w0_, w1_; \
    { \
      float v_[16] = {ka.x,ka.y,ka.z,ka.w, kc.x,kc.y,kc.z,kc.w, \
                      ke.x,ke.y,ke.z,ke.w, kg4.x,kg4.y,kg4.z,kg4.w}; \
      _Pragma("unroll") \
      for (int j_ = 0; j_ < 8; ++j_) { w0_[j_] = f2bf(v_[j_]); w1_[j_] = f2bf(v_[8+j_]); } \
    } \
    { \
      const int base_ = krow * 64 + kd; \
      const int sw_ = (krow & 7) << 3; \
      *(bf16x8*)&Ksh[NXT][(base_    ) ^ sw_] = w0_; \
      *(bf16x8*)&Ksh[NXT][(base_ + 8) ^ sw_] = w1_; \
    } \
    { \
      float r0_[8] = {va0.x,va0.y,va0.z,va0.w, va1.x,va1.y,va1.z,va1.w}; \
      float r1_[8] = {vb0.x,vb0.y,vb0.z,vb0.w, vb1.x,vb1.y,vb1.z,vb1.w}; \
      unsigned* vt_ = (unsigned*)VTsh[NXT]; \
      _Pragma("unroll") \
      for (int j_ = 0; j_ < 8; ++j_) { \
        unsigned pk_ = (unsigned)(unsigned short)f2bf(r0_[j_]) | \
                       ((unsigned)(unsigned short)f2bf(r1_[j_]) << 16); \
        const int R_ = vd + j_; \
        vt_[R_ * 32 + ((vrow >> 1) ^ ((R_ & 7) << 2))] = pk_; \
      } \
    } \
  } while (0)

#define ITER(CUR, NXT, T) do { \
    if ((T) < 15) STAGE(NXT); \
    f32x4 sacc[4]; \
    _Pragma("unroll") \
    for (int tt = 0; tt < 4; ++tt) { \
      _Pragma("unroll") \
      for (int r = 0; r < 4; ++r) sacc[tt][r] = br[r][tt] - 8.f; \
    } \
    if ((T) < 14) LOAD_KV(((T)+2) * 64); \
    if ((T) < 15) LOAD_BIAS(((T)+1) * 64); \
    _Pragma("unroll") \
    for (int tt = 0; tt < 4; ++tt) { \
      const int kr = tt * 16 + lo; \
      const int ksw = (kr & 7) << 3; \
      bf16x8 k0 = *(const bf16x8*)&Ksh[CUR][(kr * 64      + hi * 8) ^ ksw]; \
      bf16x8 k1 = *(const bf16x8*)&Ksh[CUR][(kr * 64 + 32 + hi * 8) ^ ksw]; \
      sacc[tt] = __builtin_amdgcn_mfma_f32_16x16x32_bf16(qf[0], k0, sacc[tt], 0, 0, 0); \
      sacc[tt] = __builtin_amdgcn_mfma_f32_16x16x32_bf16(qf[1], k1, sacc[tt], 0, 0, 0); \
    } \
    { \
      short* pw = Psh[w]; \
      _Pragma("unroll") \
      for (int r = 0; r < 4; ++r) { \
        const int row = hi * 4 + r; \
        const int sw = (row & 7) << 3; \
        _Pragma("unroll") \
        for (int tt = 0; tt < 4; ++tt) { \
          float p = __expf(sacc[tt][r]); \
          short pb = f2bf(p); \
          psum[r] += bf2f(pb); \
          pw[row * 64 + ((tt * 16 + lo) ^ sw)] = pb; \
        } \
      } \
      asm volatile("s_waitcnt lgkmcnt(0)" ::: "memory"); \
      bf16x8 pf0, pf1; \
      { \
        const int psw = (lo & 7) << 3; \
        pf0 = *(const bf16x8*)&pw[lo * 64 + ((     hi * 8) ^ psw)]; \
        pf1 = *(const bf16x8*)&pw[lo * 64 + ((32 + hi * 8) ^ psw)]; \
      } \
      _Pragma("unroll") \
      for (int dt = 0; dt < 4; ++dt) { \
        const int vr = dt * 16 + lo; \
        const int vsw = (vr & 7) << 3; \
        bf16x8 v0 = *(const bf16x8*)&VTsh[CUR][vr * 64 + ((     hi * 8) ^ vsw)]; \
        bf16x8 v1 = *(const bf16x8*)&VTsh[CUR][vr * 64 + ((32 + hi * 8) ^ vsw)]; \
        oacc[dt] = __builtin_amdgcn_mfma_f32_16x16x32_bf16(pf0, v0, oacc[dt], 0, 0, 0); \
        oacc[dt] = __builtin_amdgcn_mfma_f32_16x16x32_bf16(pf1, v1, oacc[dt], 0, 0, 0); \
      } \
    } \
    __syncthreads(); \
  } while (0)

  // ---- prologue: stage tile 0 into buf0, prefetch tile 1 regs + bias 0 ----
  LOAD_KV(0);
  LOAD_BIAS(0);
  STAGE(0);
  LOAD_KV(64);
  __syncthreads();

  for (int t = 0; t < 16; t += 2) {
    ITER(0, 1, t);
    ITER(1, 0, t + 1);
  }

#undef ITER
#undef STAGE
#undef LOAD_BIAS
#undef LOAD_KV

  // ---- final row-sum reduction ----
  #pragma unroll
  for (int r = 0; r < 4; ++r) {
    psum[r] += __shfl_xor(psum[r], 1, 64);
    psum[r] += __shfl_xor(psum[r], 2, 64);
    psum[r] += __shfl_xor(psum[r], 4, 64);
    psum[r] += __shfl_xor(psum[r], 8, 64);
  }

  // ---- epilogue ----
  float* ob = out + ((size_t)(b * NS + q0 + w * 16 + hi * 4) * NH + h) * ND + lo;
  #pragma unroll
  for (int r = 0; r < 4; ++r) {
    float inv = 1.f / psum[r];
    #pragma unroll
    for (int dt = 0; dt < 4; ++dt)
      ob[(size_t)r * NH * ND + dt * 16] = oacc[dt][r] * inv;
  }
}

extern "C" void kernel_launch(void* const* d_in, const int* in_sizes, int n_in,
                              void* d_out, int out_size, void* d_ws, size_t ws_size,
                              hipStream_t stream) {
  const float* qkv  = (const float*)d_in[0];
  const float* bias = (const float*)d_in[1];
  float* out = (float*)d_out;
  dim3 grid(NB * NH * (NS / 64));
  fsa_fwd<<<grid, 256, 0, stream>>>(qkv, bias, out);
}